// Round 4
// baseline (601.849 us; speedup 1.0000x reference)
//
#include <hip/hip_runtime.h>

#define B_   2
#define S_   2048
#define H_   2560
#define NH_  8
#define NKV_ 4
#define D_   256
#define SW_  1024

// qkv row layout (fp16, stride 4096): [0,2048) Q heads, [2048,3072) K, [3072,4096) V
#define QKV_LD 4096

typedef __attribute__((ext_vector_type(8))) short    short8;
typedef __attribute__((ext_vector_type(8))) _Float16 half8;
typedef __attribute__((ext_vector_type(4))) float    floatx4;
typedef __attribute__((ext_vector_type(2))) float    floatx2;
typedef __attribute__((ext_vector_type(4))) unsigned short ushort4v;

typedef unsigned int __attribute__((address_space(1))) as1_uint;
typedef unsigned int __attribute__((address_space(3))) as3_uint;

static __device__ __forceinline__ void async16(const void* g, void* l) {
    __builtin_amdgcn_global_load_lds((const as1_uint*)g, (as3_uint*)l, 16, 0, 0);
}

static __device__ __forceinline__ float bf2f(unsigned short u) {
    unsigned int x = ((unsigned int)u) << 16;
    return __builtin_bit_cast(float, x);
}
static __device__ __forceinline__ unsigned short f2bf(float f) {
    unsigned int x = __builtin_bit_cast(unsigned int, f);
    x += 0x7fffu + ((x >> 16) & 1u);
    return (unsigned short)(x >> 16);
}

// ---------------------------------------------------------------------------
// fp32 -> (hi, lo) bf16 planes.  lo = bf16(x - float(hi)); effective ~17
// mantissa bits when recombined via 3-term MFMA.
// ---------------------------------------------------------------------------
__global__ __launch_bounds__(256) void split_f32_bf16(
    const float* __restrict__ src, unsigned short* __restrict__ hi,
    unsigned short* __restrict__ lo, int n4)
{
    for (int i = blockIdx.x * 256 + threadIdx.x; i < n4; i += gridDim.x * 256) {
        floatx4 v = *(const floatx4*)(src + (size_t)i * 4);
        ushort4v h, l;
        h.x = f2bf(v.x); l.x = f2bf(v.x - bf2f(h.x));
        h.y = f2bf(v.y); l.y = f2bf(v.y - bf2f(h.y));
        h.z = f2bf(v.z); l.z = f2bf(v.z - bf2f(h.z));
        h.w = f2bf(v.w); l.w = f2bf(v.w - bf2f(h.w));
        *(ushort4v*)(hi + (size_t)i * 4) = h;
        *(ushort4v*)(lo + (size_t)i * 4) = l;
    }
}

__global__ __launch_bounds__(256) void conv_f32_bf16(
    const float* __restrict__ src, unsigned short* __restrict__ dst, int n4)
{
    for (int i = blockIdx.x * 256 + threadIdx.x; i < n4; i += gridDim.x * 256) {
        floatx4 v = *(const floatx4*)(src + (size_t)i * 4);
        ushort4v h = { f2bf(v.x), f2bf(v.y), f2bf(v.z), f2bf(v.w) };
        *(ushort4v*)(dst + (size_t)i * 4) = h;
    }
}

// ---------------------------------------------------------------------------
// Split-precision GEMM: C[M,N] = (Ah+Al)(Bh+Bl)^T ~= Ah Bh^T + Ah Bl^T + Al Bh^T
// All four operand planes bf16 [*, K] row-major, staged via global_load_lds
// width-16 (m97 structure). 128x128 tile, BK=32, 4 waves, 48 MFMA/K-step.
// C written fp16 [M][N].
// ---------------------------------------------------------------------------
__global__ __launch_bounds__(256, 2) void gemm_split(
    const unsigned short* __restrict__ Ah, const unsigned short* __restrict__ Al,
    const unsigned short* __restrict__ Bh, const unsigned short* __restrict__ Bl,
    _Float16* __restrict__ C,
    int M, int N, int K)
{
    __shared__ __align__(16) unsigned short AsH[128 * 32];
    __shared__ __align__(16) unsigned short AsL[128 * 32];
    __shared__ __align__(16) unsigned short BsH[128 * 32];
    __shared__ __align__(16) unsigned short BsL[128 * 32];

    const int tid  = threadIdx.x;
    const int lane = tid & 63, w = tid >> 6;
    const int wr = w >> 1, wc = w & 1;
    const int quad = lane >> 4, l16 = lane & 15;
    const int mBase = blockIdx.y * 128, nBase = blockIdx.x * 128;

    floatx4 acc[4][4];
    const floatx4 fzero = {0.f, 0.f, 0.f, 0.f};
#pragma unroll
    for (int i = 0; i < 4; ++i)
#pragma unroll
        for (int j = 0; j < 4; ++j) acc[i][j] = fzero;

    const int sRow = lane >> 2;
    const int sCol = (lane & 3) * 8;
    const size_t aRow = (size_t)(mBase + w * 32 + sRow);
    const size_t bRow = (size_t)(nBase + w * 32 + sRow);

    for (int kk = 0; kk < K; kk += 32) {
#pragma unroll
        for (int i = 0; i < 2; ++i) {
            const int ldsOff = (w * 32 + i * 16) * 32;
            async16(Ah + (aRow + i * 16) * K + kk + sCol, &AsH[ldsOff]);
            async16(Al + (aRow + i * 16) * K + kk + sCol, &AsL[ldsOff]);
            async16(Bh + (bRow + i * 16) * K + kk + sCol, &BsH[ldsOff]);
            async16(Bl + (bRow + i * 16) * K + kk + sCol, &BsL[ldsOff]);
        }
        __syncthreads();
        short8 afh[4], afl[4], bfh[4], bfl[4];
#pragma unroll
        for (int i = 0; i < 4; ++i) {
            const int off = (wr * 64 + i * 16 + l16) * 32 + quad * 8;
            afh[i] = *(const short8*)&AsH[off];
            afl[i] = *(const short8*)&AsL[off];
        }
#pragma unroll
        for (int j = 0; j < 4; ++j) {
            const int off = (wc * 64 + j * 16 + l16) * 32 + quad * 8;
            bfh[j] = *(const short8*)&BsH[off];
            bfl[j] = *(const short8*)&BsL[off];
        }
#pragma unroll
        for (int i = 0; i < 4; ++i)
#pragma unroll
            for (int j = 0; j < 4; ++j) {
                acc[i][j] = __builtin_amdgcn_mfma_f32_16x16x32_bf16(afh[i], bfh[j], acc[i][j], 0, 0, 0);
                acc[i][j] = __builtin_amdgcn_mfma_f32_16x16x32_bf16(afh[i], bfl[j], acc[i][j], 0, 0, 0);
                acc[i][j] = __builtin_amdgcn_mfma_f32_16x16x32_bf16(afl[i], bfh[j], acc[i][j], 0, 0, 0);
            }
        __syncthreads();
    }

    // epilogue: C/D layout col=lane&15, row=quad*4+reg (m89-verified)
#pragma unroll
    for (int i = 0; i < 4; ++i) {
        const int row0 = mBase + wr * 64 + i * 16 + quad * 4;
#pragma unroll
        for (int j = 0; j < 4; ++j) {
            const int col = nBase + wc * 64 + j * 16 + l16;
#pragma unroll
            for (int r = 0; r < 4; ++r)
                C[(size_t)(row0 + r) * N + col] = (_Float16)acc[i][j][r];
        }
    }
}

// ---------------------------------------------------------------------------
// Pure-bf16 GEMM (m97 structure), fp32 output: C[M,N] = A[M,K] @ B[N,K]^T
// ---------------------------------------------------------------------------
__global__ __launch_bounds__(256, 2) void gemm_bt_f32out(
    const unsigned short* __restrict__ A,
    const unsigned short* __restrict__ Bm,
    float* __restrict__ C,
    int M, int N, int K)
{
    __shared__ __align__(16) unsigned short As[128 * 32];
    __shared__ __align__(16) unsigned short Bs[128 * 32];

    const int tid  = threadIdx.x;
    const int lane = tid & 63, w = tid >> 6;
    const int wr = w >> 1, wc = w & 1;
    const int quad = lane >> 4, l16 = lane & 15;
    const int mBase = blockIdx.y * 128, nBase = blockIdx.x * 128;

    floatx4 acc[4][4];
    const floatx4 fzero = {0.f, 0.f, 0.f, 0.f};
#pragma unroll
    for (int i = 0; i < 4; ++i)
#pragma unroll
        for (int j = 0; j < 4; ++j) acc[i][j] = fzero;

    const int sRow = lane >> 2;
    const int sCol = (lane & 3) * 8;
    const size_t aRow = (size_t)(mBase + w * 32 + sRow);
    const size_t bRow = (size_t)(nBase + w * 32 + sRow);

    for (int kk = 0; kk < K; kk += 32) {
#pragma unroll
        for (int i = 0; i < 2; ++i) {
            async16(A  + (aRow + i * 16) * K + kk + sCol, &As[(w * 32 + i * 16) * 32]);
            async16(Bm + (bRow + i * 16) * K + kk + sCol, &Bs[(w * 32 + i * 16) * 32]);
        }
        __syncthreads();
        short8 af[4], bfv[4];
#pragma unroll
        for (int i = 0; i < 4; ++i)
            af[i] = *(const short8*)&As[(wr * 64 + i * 16 + l16) * 32 + quad * 8];
#pragma unroll
        for (int j = 0; j < 4; ++j)
            bfv[j] = *(const short8*)&Bs[(wc * 64 + j * 16 + l16) * 32 + quad * 8];
#pragma unroll
        for (int i = 0; i < 4; ++i)
#pragma unroll
            for (int j = 0; j < 4; ++j)
                acc[i][j] = __builtin_amdgcn_mfma_f32_16x16x32_bf16(af[i], bfv[j], acc[i][j], 0, 0, 0);
        __syncthreads();
    }

#pragma unroll
    for (int i = 0; i < 4; ++i) {
        const int row0 = mBase + wr * 64 + i * 16 + quad * 4;
#pragma unroll
        for (int j = 0; j < 4; ++j) {
            const int col = nBase + wc * 64 + j * 16 + l16;
#pragma unroll
            for (int r = 0; r < 4; ++r)
                C[(size_t)(row0 + r) * N + col] = acc[i][j][r];
        }
    }
}

// ---------------------------------------------------------------------------
// IN-PLACE RMSNorm (per 256-dim head vector) + RoPE for q/k, plain RMS for v.
// ---------------------------------------------------------------------------
__global__ __launch_bounds__(256) void rmsrope_inplace(
    _Float16* __restrict__ qkv,        // [4096][4096] fp16
    const float* __restrict__ cosT,    // [S][D] fp32
    const float* __restrict__ sinT,
    const float* __restrict__ qw,      // [D] fp32
    const float* __restrict__ kw)
{
    const int t = blockIdx.x;                // b*S + s
    const int s = t & (S_ - 1);
    const int tid = threadIdx.x, lane = tid & 63, w = tid >> 6;
    _Float16* row = qkv + (size_t)t * QKV_LD;
    const int d0 = lane * 2, d1 = 128 + lane * 2;

    floatx2 c0 = *(const floatx2*)(cosT + (size_t)s * D_ + d0);
    floatx2 c1 = *(const floatx2*)(cosT + (size_t)s * D_ + d1);
    floatx2 s0 = *(const floatx2*)(sinT + (size_t)s * D_ + d0);
    floatx2 s1 = *(const floatx2*)(sinT + (size_t)s * D_ + d1);
    floatx2 qw0 = *(const floatx2*)(qw + d0), qw1 = *(const floatx2*)(qw + d1);
    floatx2 kw0 = *(const floatx2*)(kw + d0), kw1 = *(const floatx2*)(kw + d1);

#pragma unroll
    for (int p = 0; p < 4; ++p) {
        const int v = w + p * 4;             // 0..15, wave-uniform
        _Float16* x = row + v * D_;
        float x0a = (float)x[d0], x0b = (float)x[d0 + 1];
        float x1a = (float)x[d1], x1b = (float)x[d1 + 1];
        float ss = x0a * x0a + x0b * x0b + x1a * x1a + x1b * x1b;
#pragma unroll
        for (int off = 32; off > 0; off >>= 1) ss += __shfl_xor(ss, off, 64);
        const float rinv = rsqrtf(ss * (1.0f / 256.0f) + 1e-6f);
        if (v < 8) {
            const float y0a = x0a * rinv * (1.f + qw0.x), y0b = x0b * rinv * (1.f + qw0.y);
            const float y1a = x1a * rinv * (1.f + qw1.x), y1b = x1b * rinv * (1.f + qw1.y);
            x[d0] = (_Float16)(y0a * c0.x - y1a * s0.x);
            x[d0 + 1] = (_Float16)(y0b * c0.y - y1b * s0.y);
            x[d1] = (_Float16)(y1a * c1.x + y0a * s1.x);
            x[d1 + 1] = (_Float16)(y1b * c1.y + y0b * s1.y);
        } else if (v < 12) {
            const float y0a = x0a * rinv * (1.f + kw0.x), y0b = x0b * rinv * (1.f + kw0.y);
            const float y1a = x1a * rinv * (1.f + kw1.x), y1b = x1b * rinv * (1.f + kw1.y);
            x[d0] = (_Float16)(y0a * c0.x - y1a * s0.x);
            x[d0 + 1] = (_Float16)(y0b * c0.y - y1b * s0.y);
            x[d1] = (_Float16)(y1a * c1.x + y0a * s1.x);
            x[d1 + 1] = (_Float16)(y1b * c1.y + y0b * s1.y);
        } else {
            x[d0] = (_Float16)(x0a * rinv);
            x[d0 + 1] = (_Float16)(x0b * rinv);
            x[d1] = (_Float16)(x1a * rinv);
            x[d1 + 1] = (_Float16)(x1b * rinv);
        }
    }
}

// ---------------------------------------------------------------------------
// Flash attention, causal + sliding window (analytic mask), scale = 1.0.
// ---------------------------------------------------------------------------
#define KS_STRIDE 264
#define VS_STRIDE 40
#define PS_STRIDE 40

__global__ __launch_bounds__(256, 2) void attn_kernel(
    const _Float16* __restrict__ qkv,  // [B*S][4096] fp16 (post rms+rope)
    unsigned short* __restrict__ Oa)   // [B*S][NH*D] bf16
{
    __shared__ __align__(16) _Float16 Ks[32 * KS_STRIDE];
    __shared__ __align__(16) _Float16 Vs[256 * VS_STRIDE];
    __shared__ __align__(16) _Float16 Ps[4][16 * PS_STRIDE];

    const int qb = blockIdx.x * 64;
    const int h = blockIdx.y, b = blockIdx.z;
    const int kvh = h >> 1;                       // repeat_interleave(2)
    const int tid = threadIdx.x, lane = tid & 63, w = tid >> 6;
    const int quad = lane >> 4, l16 = lane & 15;

    const _Float16* Qrow = qkv + ((size_t)(b * S_ + qb + w * 16 + l16)) * QKV_LD + h * D_;
    half8 qf[8];
#pragma unroll
    for (int kst = 0; kst < 8; ++kst)
        qf[kst] = *(const half8*)(Qrow + kst * 32 + quad * 8);

    floatx4 o[16];
    const floatx4 fzero = {0.f, 0.f, 0.f, 0.f};
#pragma unroll
    for (int dt = 0; dt < 16; ++dt) o[dt] = fzero;
    float mrow[4] = {-1e30f, -1e30f, -1e30f, -1e30f};
    float lrow[4] = {0.f, 0.f, 0.f, 0.f};

    const _Float16* Kbase = qkv + (size_t)(b * S_) * QKV_LD + 2048 + kvh * D_;
    const _Float16* Vbase = qkv + (size_t)(b * S_) * QKV_LD + 3072 + kvh * D_;
    const int kb_start = (qb >= SW_) ? qb - SW_ : 0;
    const int kb_end = qb + 32;

    for (int kb = kb_start; kb <= kb_end; kb += 32) {
#pragma unroll
        for (int p = 0; p < 4; ++p) {
            const int c = tid + p * 256;
            const int r = c >> 5, off = (c & 31) * 8;
            *(half8*)&Ks[r * KS_STRIDE + off] = *(const half8*)(Kbase + (size_t)(kb + r) * QKV_LD + off);
        }
#pragma unroll
        for (int p = 0; p < 4; ++p) {
            const int c = tid + p * 256;
            const int r = c & 31, vd0 = (c >> 5) * 8;
            half8 vv = *(const half8*)(Vbase + (size_t)(kb + r) * QKV_LD + vd0);
#pragma unroll
            for (int j = 0; j < 8; ++j)
                Vs[(vd0 + j) * VS_STRIDE + r] = vv[j];
        }
        __syncthreads();

        floatx4 sacc[2];
        sacc[0] = fzero; sacc[1] = fzero;
#pragma unroll
        for (int jt = 0; jt < 2; ++jt)
#pragma unroll
            for (int kst = 0; kst < 8; ++kst) {
                half8 kf = *(const half8*)&Ks[(jt * 16 + l16) * KS_STRIDE + kst * 32 + quad * 8];
                sacc[jt] = __builtin_amdgcn_mfma_f32_16x16x32_f16(qf[kst], kf, sacc[jt], 0, 0, 0);
            }

        const int q0 = qb + w * 16 + quad * 4;
        float sval[2][4], tmax[4];
#pragma unroll
        for (int r = 0; r < 4; ++r) tmax[r] = -1e30f;
#pragma unroll
        for (int jt = 0; jt < 2; ++jt) {
            const int kg = kb + jt * 16 + l16;
#pragma unroll
            for (int r = 0; r < 4; ++r) {
                const int qg = q0 + r;
                const bool ok = (kg <= qg) && (kg + SW_ > qg);
                const float vv = ok ? sacc[jt][r] : -1e30f;
                sval[jt][r] = vv;
                tmax[r] = fmaxf(tmax[r], vv);
            }
        }
#pragma unroll
        for (int r = 0; r < 4; ++r) {
#pragma unroll
            for (int off = 1; off < 16; off <<= 1)
                tmax[r] = fmaxf(tmax[r], __shfl_xor(tmax[r], off, 64));
            const float mnew = fmaxf(mrow[r], tmax[r]);
            const float alpha = __expf(mrow[r] - mnew);
            mrow[r] = mnew;
            lrow[r] *= alpha;
            tmax[r] = alpha;                 // reuse as alpha
        }
        float rsum[4] = {0.f, 0.f, 0.f, 0.f};
#pragma unroll
        for (int jt = 0; jt < 2; ++jt)
#pragma unroll
            for (int r = 0; r < 4; ++r) {
                float pv = __expf(sval[jt][r] - mrow[r]);
                pv = (sval[jt][r] <= -1e29f) ? 0.0f : pv;
                rsum[r] += pv;
                Ps[w][(quad * 4 + r) * PS_STRIDE + jt * 16 + l16] = (_Float16)pv;
            }
#pragma unroll
        for (int r = 0; r < 4; ++r) {
#pragma unroll
            for (int off = 1; off < 16; off <<= 1)
                rsum[r] += __shfl_xor(rsum[r], off, 64);
            lrow[r] += rsum[r];
        }
#pragma unroll
        for (int dt = 0; dt < 16; ++dt)
#pragma unroll
            for (int r = 0; r < 4; ++r) o[dt][r] *= tmax[r];

        half8 pa = *(const half8*)&Ps[w][l16 * PS_STRIDE + quad * 8];
#pragma unroll
        for (int dt = 0; dt < 16; ++dt) {
            half8 vf = *(const half8*)&Vs[(dt * 16 + l16) * VS_STRIDE + quad * 8];
            o[dt] = __builtin_amdgcn_mfma_f32_16x16x32_f16(pa, vf, o[dt], 0, 0, 0);
        }
        __syncthreads();
    }

    const int qrow = qb + w * 16 + quad * 4;
#pragma unroll
    for (int r = 0; r < 4; ++r) {
        const float inv = (lrow[r] > 0.f) ? (1.0f / lrow[r]) : 0.f;
        unsigned short* orow = Oa + ((size_t)(b * S_ + qrow + r)) * (NH_ * D_) + h * D_;
#pragma unroll
        for (int dt = 0; dt < 16; ++dt)
            orow[dt * 16 + l16] = f2bf(o[dt][r] * inv);
    }
}

// ---------------------------------------------------------------------------
extern "C" void kernel_launch(void* const* d_in, const int* in_sizes, int n_in,
                              void* d_out, int out_size, void* d_ws, size_t ws_size,
                              hipStream_t stream)
{
    (void)in_sizes; (void)n_in; (void)out_size; (void)ws_size;
    const float* hid  = (const float*)d_in[0];
    // d_in[1] = attention_mask (unused: analytic causal+window mask is exact)
    const float* cosT = (const float*)d_in[2];
    const float* sinT = (const float*)d_in[3];
    const float* Wq   = (const float*)d_in[4];
    const float* Wk   = (const float*)d_in[5];
    const float* Wv   = (const float*)d_in[6];
    const float* Wo   = (const float*)d_in[7];
    const float* qw   = (const float*)d_in[8];
    const float* kw   = (const float*)d_in[9];
    float* out = (float*)d_out;

    // workspace layout (bytes; ~138 MB total)
    char* ws = (char*)d_ws;
    _Float16*       qkv   = (_Float16*)(ws);                           // 33,554,432
    unsigned short* attn  = (unsigned short*)(ws + 33554432ull);       // 16,777,216
    unsigned short* hidH  = (unsigned short*)(ws + 50331648ull);       // 20,971,520
    unsigned short* hidL  = (unsigned short*)(ws + 71303168ull);       // 20,971,520
    unsigned short* wH    = (unsigned short*)(ws + 92274688ull);       // 20,971,520 [4096][2560]
    unsigned short* wL    = (unsigned short*)(ws + 113246208ull);      // 20,971,520
    unsigned short* woB   = (unsigned short*)(ws + 134217728ull);      // 10,485,760 [2560][2048]

    const int nHid = 4096 * 2560 / 4;          // fp32x4 groups
    const int nWq  = 2048 * 2560 / 4;
    const int nWkv = 1024 * 2560 / 4;
    const int nWo  = 2560 * 2048 / 4;

    // 0) precision-split conversions
    split_f32_bf16<<<2048, 256, 0, stream>>>(hid, hidH, hidL, nHid);
    split_f32_bf16<<<1024, 256, 0, stream>>>(Wq, wH, wL, nWq);
    split_f32_bf16<<<512,  256, 0, stream>>>(Wk, wH + 2048 * 2560, wL + 2048 * 2560, nWkv);
    split_f32_bf16<<<512,  256, 0, stream>>>(Wv, wH + 3072 * 2560, wL + 3072 * 2560, nWkv);
    conv_f32_bf16 <<<1024, 256, 0, stream>>>(Wo, woB, nWo);

    // 1) QKV projection, split precision: -> fp16 [4096][4096]
    gemm_split<<<dim3(32, 32), 256, 0, stream>>>(hidH, hidL, wH, wL, qkv, 4096, 4096, 2560);
    // 2) in-place RMSNorm + RoPE on qkv
    rmsrope_inplace<<<4096, 256, 0, stream>>>(qkv, cosT, sinT, qw, kw);
    // 3) flash attention: qkv -> attn [4096][2048] bf16
    attn_kernel<<<dim3(32, 8, 2), 256, 0, stream>>>(qkv, attn);
    // 4) output projection: bf16 [4096,2048] @ Wo^T -> fp32 out [4096][2560]
    gemm_bt_f32out<<<dim3(20, 32), 256, 0, stream>>>(attn, woB, out, 4096, 2560, 2048);
}

// Round 5
// 453.249 us; speedup vs baseline: 1.3279x; 1.3279x over previous
//
#include <hip/hip_runtime.h>

#define B_   2
#define S_   2048
#define H_   2560
#define NH_  8
#define NKV_ 4
#define D_   256
#define SW_  1024

// qkv row layout (fp16, stride 4096): [0,2048) Q heads, [2048,3072) K, [3072,4096) V
#define QKV_LD 4096

typedef __attribute__((ext_vector_type(8))) short    short8;
typedef __attribute__((ext_vector_type(8))) _Float16 half8;
typedef __attribute__((ext_vector_type(4))) _Float16 half4;
typedef __attribute__((ext_vector_type(4))) float    floatx4;
typedef __attribute__((ext_vector_type(2))) float    floatx2;

typedef unsigned int __attribute__((address_space(1))) as1_uint;
typedef unsigned int __attribute__((address_space(3))) as3_uint;

static __device__ __forceinline__ void async16(const void* g, void* l) {
    __builtin_amdgcn_global_load_lds((const as1_uint*)g, (as3_uint*)l, 16, 0, 0);
}

// ---------------------------------------------------------------------------
// fp32 -> fp16 conversion (vectorized x4)
// ---------------------------------------------------------------------------
__global__ __launch_bounds__(256) void conv_f32_f16(
    const float* __restrict__ src, _Float16* __restrict__ dst, int n4)
{
    for (int i = blockIdx.x * 256 + threadIdx.x; i < n4; i += gridDim.x * 256) {
        floatx4 v = *(const floatx4*)(src + (size_t)i * 4);
        half4 h = { (_Float16)v.x, (_Float16)v.y, (_Float16)v.z, (_Float16)v.w };
        *(half4*)(dst + (size_t)i * 4) = h;
    }
}

// ---------------------------------------------------------------------------
// fp16 GEMM (m97 structure): C[M,N] = A[M,K] @ B[N,K]^T, both fp16 row-major,
// staged via global_load_lds width-16. 128x128 tile, BK=32, 4 waves (2x2 of
// 64x64), mfma_f32_16x16x32_f16. C fp16 (C_FP32=0) or fp32 (C_FP32=1).
// ---------------------------------------------------------------------------
template <int C_FP32>
__global__ __launch_bounds__(256, 2) void gemm_f16(
    const _Float16* __restrict__ A,
    const _Float16* __restrict__ Bm,
    void* __restrict__ Cv,
    int M, int N, int K)
{
    __shared__ __align__(16) _Float16 As[128 * 32];
    __shared__ __align__(16) _Float16 Bs[128 * 32];

    const int tid  = threadIdx.x;
    const int lane = tid & 63, w = tid >> 6;
    const int wr = w >> 1, wc = w & 1;
    const int quad = lane >> 4, l16 = lane & 15;
    const int mBase = blockIdx.y * 128, nBase = blockIdx.x * 128;

    floatx4 acc[4][4];
    const floatx4 fzero = {0.f, 0.f, 0.f, 0.f};
#pragma unroll
    for (int i = 0; i < 4; ++i)
#pragma unroll
        for (int j = 0; j < 4; ++j) acc[i][j] = fzero;

    const int sRow = lane >> 2;         // 0..15 (row within 16-row chunk)
    const int sCol = (lane & 3) * 8;    // element offset within 32-elem row
    const size_t aRow = (size_t)(mBase + w * 32 + sRow);
    const size_t bRow = (size_t)(nBase + w * 32 + sRow);

    for (int kk = 0; kk < K; kk += 32) {
#pragma unroll
        for (int i = 0; i < 2; ++i) {
            async16(A  + (aRow + i * 16) * K + kk + sCol, &As[(w * 32 + i * 16) * 32]);
            async16(Bm + (bRow + i * 16) * K + kk + sCol, &Bs[(w * 32 + i * 16) * 32]);
        }
        __syncthreads();
        half8 af[4], bfv[4];
#pragma unroll
        for (int i = 0; i < 4; ++i)
            af[i] = *(const half8*)&As[(wr * 64 + i * 16 + l16) * 32 + quad * 8];
#pragma unroll
        for (int j = 0; j < 4; ++j)
            bfv[j] = *(const half8*)&Bs[(wc * 64 + j * 16 + l16) * 32 + quad * 8];
#pragma unroll
        for (int i = 0; i < 4; ++i)
#pragma unroll
            for (int j = 0; j < 4; ++j)
                acc[i][j] = __builtin_amdgcn_mfma_f32_16x16x32_f16(af[i], bfv[j], acc[i][j], 0, 0, 0);
        __syncthreads();
    }

    // epilogue: C/D layout col=lane&15, row=quad*4+reg (m89-verified)
#pragma unroll
    for (int i = 0; i < 4; ++i) {
        const int row0 = mBase + wr * 64 + i * 16 + quad * 4;
#pragma unroll
        for (int j = 0; j < 4; ++j) {
            const int col = nBase + wc * 64 + j * 16 + l16;
#pragma unroll
            for (int r = 0; r < 4; ++r) {
                const size_t idx = (size_t)(row0 + r) * N + col;
                if (C_FP32) ((float*)Cv)[idx] = acc[i][j][r];
                else        ((_Float16*)Cv)[idx] = (_Float16)acc[i][j][r];
            }
        }
    }
}

// ---------------------------------------------------------------------------
// IN-PLACE RMSNorm (per 256-dim head vector) + RoPE for q/k, plain RMS for v.
// One block per token; wave w handles head-vectors {w, w+4, w+8, w+12}.
// Lane holds elems {2L,2L+1} and {128+2L,128+2L+1} so RoPE pairing is
// register-local; reads complete into registers before writeback.
// ---------------------------------------------------------------------------
__global__ __launch_bounds__(256) void rmsrope_inplace(
    _Float16* __restrict__ qkv,        // [4096][4096] fp16
    const float* __restrict__ cosT,    // [S][D] fp32
    const float* __restrict__ sinT,
    const float* __restrict__ qw,      // [D] fp32
    const float* __restrict__ kw)
{
    const int t = blockIdx.x;                // b*S + s
    const int s = t & (S_ - 1);
    const int tid = threadIdx.x, lane = tid & 63, w = tid >> 6;
    _Float16* row = qkv + (size_t)t * QKV_LD;
    const int d0 = lane * 2, d1 = 128 + lane * 2;

    floatx2 c0 = *(const floatx2*)(cosT + (size_t)s * D_ + d0);
    floatx2 c1 = *(const floatx2*)(cosT + (size_t)s * D_ + d1);
    floatx2 s0 = *(const floatx2*)(sinT + (size_t)s * D_ + d0);
    floatx2 s1 = *(const floatx2*)(sinT + (size_t)s * D_ + d1);
    floatx2 qw0 = *(const floatx2*)(qw + d0), qw1 = *(const floatx2*)(qw + d1);
    floatx2 kw0 = *(const floatx2*)(kw + d0), kw1 = *(const floatx2*)(kw + d1);

#pragma unroll
    for (int p = 0; p < 4; ++p) {
        const int v = w + p * 4;             // 0..15, wave-uniform
        _Float16* x = row + v * D_;
        float x0a = (float)x[d0], x0b = (float)x[d0 + 1];
        float x1a = (float)x[d1], x1b = (float)x[d1 + 1];
        float ss = x0a * x0a + x0b * x0b + x1a * x1a + x1b * x1b;
#pragma unroll
        for (int off = 32; off > 0; off >>= 1) ss += __shfl_xor(ss, off, 64);
        const float rinv = rsqrtf(ss * (1.0f / 256.0f) + 1e-6f);
        if (v < 8) {
            const float y0a = x0a * rinv * (1.f + qw0.x), y0b = x0b * rinv * (1.f + qw0.y);
            const float y1a = x1a * rinv * (1.f + qw1.x), y1b = x1b * rinv * (1.f + qw1.y);
            x[d0] = (_Float16)(y0a * c0.x - y1a * s0.x);
            x[d0 + 1] = (_Float16)(y0b * c0.y - y1b * s0.y);
            x[d1] = (_Float16)(y1a * c1.x + y0a * s1.x);
            x[d1 + 1] = (_Float16)(y1b * c1.y + y0b * s1.y);
        } else if (v < 12) {
            const float y0a = x0a * rinv * (1.f + kw0.x), y0b = x0b * rinv * (1.f + kw0.y);
            const float y1a = x1a * rinv * (1.f + kw1.x), y1b = x1b * rinv * (1.f + kw1.y);
            x[d0] = (_Float16)(y0a * c0.x - y1a * s0.x);
            x[d0 + 1] = (_Float16)(y0b * c0.y - y1b * s0.y);
            x[d1] = (_Float16)(y1a * c1.x + y0a * s1.x);
            x[d1 + 1] = (_Float16)(y1b * c1.y + y0b * s1.y);
        } else {
            x[d0] = (_Float16)(x0a * rinv);
            x[d0 + 1] = (_Float16)(x0b * rinv);
            x[d1] = (_Float16)(x1a * rinv);
            x[d1 + 1] = (_Float16)(x1b * rinv);
        }
    }
}

// ---------------------------------------------------------------------------
// Flash attention, causal + sliding window (analytic mask), scale = 1.0.
// Reads Q/K/V from qkv (row stride 4096). 64 queries/block, 32-key tiles.
// ---------------------------------------------------------------------------
#define KS_STRIDE 264
#define VS_STRIDE 40
#define PS_STRIDE 40

__global__ __launch_bounds__(256, 2) void attn_kernel(
    const _Float16* __restrict__ qkv,  // [B*S][4096] fp16 (post rms+rope)
    _Float16* __restrict__ Oa)         // [B*S][NH*D] fp16
{
    __shared__ __align__(16) _Float16 Ks[32 * KS_STRIDE];
    __shared__ __align__(16) _Float16 Vs[256 * VS_STRIDE];
    __shared__ __align__(16) _Float16 Ps[4][16 * PS_STRIDE];

    const int qb = blockIdx.x * 64;
    const int h = blockIdx.y, b = blockIdx.z;
    const int kvh = h >> 1;                       // repeat_interleave(2)
    const int tid = threadIdx.x, lane = tid & 63, w = tid >> 6;
    const int quad = lane >> 4, l16 = lane & 15;

    // Q fragments: A-layout m=lane&15, k=quad*8+j
    const _Float16* Qrow = qkv + ((size_t)(b * S_ + qb + w * 16 + l16)) * QKV_LD + h * D_;
    half8 qf[8];
#pragma unroll
    for (int kst = 0; kst < 8; ++kst)
        qf[kst] = *(const half8*)(Qrow + kst * 32 + quad * 8);

    floatx4 o[16];
    const floatx4 fzero = {0.f, 0.f, 0.f, 0.f};
#pragma unroll
    for (int dt = 0; dt < 16; ++dt) o[dt] = fzero;
    float mrow[4] = {-1e30f, -1e30f, -1e30f, -1e30f};
    float lrow[4] = {0.f, 0.f, 0.f, 0.f};

    const _Float16* Kbase = qkv + (size_t)(b * S_) * QKV_LD + 2048 + kvh * D_;
    const _Float16* Vbase = qkv + (size_t)(b * S_) * QKV_LD + 3072 + kvh * D_;
    const int kb_start = (qb >= SW_) ? qb - SW_ : 0;
    const int kb_end = qb + 32;  // inclusive; last tile covers keys qb+32..qb+63

    for (int kb = kb_start; kb <= kb_end; kb += 32) {
        // stage K tile [32 keys][256 d]
#pragma unroll
        for (int p = 0; p < 4; ++p) {
            const int c = tid + p * 256;
            const int r = c >> 5, off = (c & 31) * 8;
            *(half8*)&Ks[r * KS_STRIDE + off] = *(const half8*)(Kbase + (size_t)(kb + r) * QKV_LD + off);
        }
        // stage V tile transposed: read V[key][d] 16B chunks, scatter to Vs[d][key]
#pragma unroll
        for (int p = 0; p < 4; ++p) {
            const int c = tid + p * 256;
            const int r = c & 31, vd0 = (c >> 5) * 8;
            half8 vv = *(const half8*)(Vbase + (size_t)(kb + r) * QKV_LD + vd0);
#pragma unroll
            for (int j = 0; j < 8; ++j)
                Vs[(vd0 + j) * VS_STRIDE + r] = vv[j];
        }
        __syncthreads();

        // S = Q K^T  (wave: 16 queries x 32 keys)
        floatx4 sacc[2];
        sacc[0] = fzero; sacc[1] = fzero;
#pragma unroll
        for (int jt = 0; jt < 2; ++jt)
#pragma unroll
            for (int kst = 0; kst < 8; ++kst) {
                half8 kf = *(const half8*)&Ks[(jt * 16 + l16) * KS_STRIDE + kst * 32 + quad * 8];
                sacc[jt] = __builtin_amdgcn_mfma_f32_16x16x32_f16(qf[kst], kf, sacc[jt], 0, 0, 0);
            }

        // analytic mask + online softmax (row = quad*4+reg, col = lane&15)
        const int q0 = qb + w * 16 + quad * 4;
        float sval[2][4], tmax[4];
#pragma unroll
        for (int r = 0; r < 4; ++r) tmax[r] = -1e30f;
#pragma unroll
        for (int jt = 0; jt < 2; ++jt) {
            const int kg = kb + jt * 16 + l16;
#pragma unroll
            for (int r = 0; r < 4; ++r) {
                const int qg = q0 + r;
                const bool ok = (kg <= qg) && (kg + SW_ > qg);
                const float vv = ok ? sacc[jt][r] : -1e30f;
                sval[jt][r] = vv;
                tmax[r] = fmaxf(tmax[r], vv);
            }
        }
#pragma unroll
        for (int r = 0; r < 4; ++r) {
#pragma unroll
            for (int off = 1; off < 16; off <<= 1)
                tmax[r] = fmaxf(tmax[r], __shfl_xor(tmax[r], off, 64));
            const float mnew = fmaxf(mrow[r], tmax[r]);
            const float alpha = __expf(mrow[r] - mnew);
            mrow[r] = mnew;
            lrow[r] *= alpha;
            tmax[r] = alpha;                 // reuse as alpha
        }
        float rsum[4] = {0.f, 0.f, 0.f, 0.f};
#pragma unroll
        for (int jt = 0; jt < 2; ++jt)
#pragma unroll
            for (int r = 0; r < 4; ++r) {
                float pv = __expf(sval[jt][r] - mrow[r]);
                pv = (sval[jt][r] <= -1e29f) ? 0.0f : pv;   // masked -> exact 0
                rsum[r] += pv;
                Ps[w][(quad * 4 + r) * PS_STRIDE + jt * 16 + l16] = (_Float16)pv;
            }
#pragma unroll
        for (int r = 0; r < 4; ++r) {
#pragma unroll
            for (int off = 1; off < 16; off <<= 1)
                rsum[r] += __shfl_xor(rsum[r], off, 64);
            lrow[r] += rsum[r];
        }
        // rescale O by alpha
#pragma unroll
        for (int dt = 0; dt < 16; ++dt)
#pragma unroll
            for (int r = 0; r < 4; ++r) o[dt][r] *= tmax[r];

        // O += P V   (P LDS round-trip C-layout -> A-layout, m120 pattern)
        half8 pa = *(const half8*)&Ps[w][l16 * PS_STRIDE + quad * 8];
#pragma unroll
        for (int dt = 0; dt < 16; ++dt) {
            half8 vf = *(const half8*)&Vs[(dt * 16 + l16) * VS_STRIDE + quad * 8];
            o[dt] = __builtin_amdgcn_mfma_f32_16x16x32_f16(pa, vf, o[dt], 0, 0, 0);
        }
        __syncthreads();
    }

    // epilogue: divide by l, store fp16 [B*S][NH*D]
    const int qrow = qb + w * 16 + quad * 4;
#pragma unroll
    for (int r = 0; r < 4; ++r) {
        const float inv = (lrow[r] > 0.f) ? (1.0f / lrow[r]) : 0.f;
        _Float16* orow = Oa + ((size_t)(b * S_ + qrow + r)) * (NH_ * D_) + h * D_;
#pragma unroll
        for (int dt = 0; dt < 16; ++dt)
            orow[dt * 16 + l16] = (_Float16)(o[dt][r] * inv);
    }
}

// ---------------------------------------------------------------------------
extern "C" void kernel_launch(void* const* d_in, const int* in_sizes, int n_in,
                              void* d_out, int out_size, void* d_ws, size_t ws_size,
                              hipStream_t stream)
{
    (void)in_sizes; (void)n_in; (void)out_size; (void)ws_size;
    const float* hid  = (const float*)d_in[0];
    // d_in[1] = attention_mask (unused: analytic causal+window mask is exact)
    const float* cosT = (const float*)d_in[2];
    const float* sinT = (const float*)d_in[3];
    const float* Wq   = (const float*)d_in[4];
    const float* Wk   = (const float*)d_in[5];
    const float* Wv   = (const float*)d_in[6];
    const float* Wo   = (const float*)d_in[7];
    const float* qw   = (const float*)d_in[8];
    const float* kw   = (const float*)d_in[9];
    float* out = (float*)d_out;

    // workspace layout (bytes; ~98 MB total)
    char* ws = (char*)d_ws;
    _Float16* qkv  = (_Float16*)(ws);                     // 33,554,432  [4096][4096]
    _Float16* attn = (_Float16*)(ws + 33554432ull);       // 16,777,216  [4096][2048]
    _Float16* hidH = (_Float16*)(ws + 50331648ull);       // 20,971,520  [4096][2560]
    _Float16* wQKV = (_Float16*)(ws + 71303168ull);       // 20,971,520  [4096][2560] (Wq;Wk;Wv)
    _Float16* woH  = (_Float16*)(ws + 92274688ull);       // 10,485,760  [2560][2048]

    const int nHid = 4096 * 2560 / 4;
    const int nWq  = 2048 * 2560 / 4;
    const int nWkv = 1024 * 2560 / 4;
    const int nWo  = 2560 * 2048 / 4;

    // 0) fp32 -> fp16 conversions
    conv_f32_f16<<<2048, 256, 0, stream>>>(hid, hidH, nHid);
    conv_f32_f16<<<1024, 256, 0, stream>>>(Wq, wQKV, nWq);
    conv_f32_f16<<<512,  256, 0, stream>>>(Wk, wQKV + (size_t)2048 * 2560, nWkv);
    conv_f32_f16<<<512,  256, 0, stream>>>(Wv, wQKV + (size_t)3072 * 2560, nWkv);
    conv_f32_f16<<<1024, 256, 0, stream>>>(Wo, woH, nWo);

    // 1) QKV projection (fp16 MFMA): -> fp16 [4096][4096]
    gemm_f16<0><<<dim3(32, 32), 256, 0, stream>>>(hidH, wQKV, qkv, 4096, 4096, 2560);
    // 2) in-place RMSNorm + RoPE on qkv
    rmsrope_inplace<<<4096, 256, 0, stream>>>(qkv, cosT, sinT, qw, kw);
    // 3) flash attention: qkv -> attn [4096][2048] fp16
    attn_kernel<<<dim3(32, 8, 2), 256, 0, stream>>>(qkv, attn);
    // 4) output projection: fp16 [4096,2048] @ Wo^T -> fp32 out [4096][2560]
    gemm_f16<1><<<dim3(20, 32), 256, 0, stream>>>(attn, woH, out, 4096, 2560, 2048);
}